// Round 1
// baseline (370.216 us; speedup 1.0000x reference)
//
#include <hip/hip_runtime.h>
#include <math.h>

// Problem constants (B=8, Cin=Cout=64, H=W=64, 3x3 kernel pad 1)
#define NB     8
#define NC     64
#define HW     4096           // 64*64
#define PLANE  2097152        // NB*NC*HW

// Workspace layout (float-slot offsets)
#define WS_WB     0           // bf16 wB[8][72][64][8]   (294912 bf16 = 147456 f)
#define WS_OWB    147456      // bf16 owB[8][72][32][8]  (147456 bf16 = 73728 f)
#define WS_OB     221184      // f32 obAll[8][27]
#define WS_GATES  221400      // f32 gates_scr[4][8][64][4096] = 8388608 (D-scrambled)
#define WS_XT     8610008     // bf16 xT[8][4096][64] HWC  (1048576 f)
#define WS_HT     9658584     // bf16 hT[8][4096][64] HWC  (1048576 f)
// total = 10707160 floats = 42.8 MB

typedef __bf16 bf16x8 __attribute__((ext_vector_type(8)));
typedef float  f32x4  __attribute__((ext_vector_type(4)));

struct Params {
    const float* x; const float* h; const float* c;
    const float* w[8]; const float* ow[8]; const float* ob[8];
    const float* bi; const float* bf; const float* bc; const float* bo;
    const float* wci; const float* wcf; const float* wco;
    float* out; float* ws;
};

__device__ __forceinline__ float sigf(float v) { return 1.f / (1.f + __expf(-v)); }
__device__ __forceinline__ float tanhfast(float v) {
    return 1.f - 2.f / (__expf(2.f * v) + 1.f);
}
__device__ __forceinline__ unsigned short f2bf(float v) {
    __bf16 b = (__bf16)v;
    return __builtin_bit_cast(unsigned short, b);
}
// bf16 pair unpack: lo/hi halves of a dword -> f32 (1 inst each)
__device__ __forceinline__ float blo(unsigned d) { return __builtin_bit_cast(float, d << 16); }
__device__ __forceinline__ float bhi(unsigned d) { return __builtin_bit_cast(float, d & 0xffff0000u); }

// ---------------------------------------------------------------------------
// K0 (merged): weight B-frag packing + biases (blocks 0..1728), and
//   CHW fp32 -> HWC bf16 transpose of x/h (blocks 1729..2752).
// ---------------------------------------------------------------------------
__global__ __launch_bounds__(256) void k0_prep(Params p) {
    if (blockIdx.x < 1729) {
        int i = blockIdx.x * 256 + threadIdx.x;
        unsigned short* wb  = (unsigned short*)(p.ws + WS_WB);
        unsigned short* owb = (unsigned short*)(p.ws + WS_OWB);
        if (i < 294912) {
            int br = i / 36864; int r = i % 36864;
            int kgrp = r >> 9; int o = (r >> 3) & 63; int j = r & 7;
            int k = kgrp * 8 + j;
            int ktap = k >> 6; int c = k & 63;
            wb[i] = f2bf(p.w[br][(o * 64 + c) * 9 + ktap]);
        } else if (i < 294912 + 147456) {
            int ii = i - 294912;
            int br = ii / 18432; int r = ii % 18432;
            int kgrp = r >> 8; int o = (r >> 3) & 31; int j = r & 7;
            int k = kgrp * 8 + j;
            int ktap = k >> 6; int c = k & 63;
            float v = (o < 27) ? p.ow[br][(o * 64 + c) * 9 + ktap] : 0.f;
            owb[ii] = f2bf(v);
        } else if (i < 294912 + 147456 + 216) {
            int ii = i - 442368;
            int br = ii / 27; int j = ii % 27;
            p.ws[WS_OB + ii] = p.ob[br][j];
        }
        return;
    }
    __shared__ float tile[64][65];
    int bid = blockIdx.x - 1729;
    int row = bid & 63; int b = (bid >> 6) & 7; int ten = bid >> 9;
    const float* src = ten ? p.h : p.x;
    unsigned short* dst = (unsigned short*)(p.ws + (ten ? WS_HT : WS_XT));
    int t = threadIdx.x; int lane = t & 63; int w4 = t >> 6;
#pragma unroll
    for (int i = 0; i < 16; ++i) {
        int c = i * 4 + w4;
        tile[c][lane] = src[((size_t)(b * 64 + c) << 12) + row * 64 + lane];
    }
    __syncthreads();
#pragma unroll
    for (int i = 0; i < 16; ++i) {
        int px = i * 4 + w4;
        dst[((size_t)(b * 4096 + row * 64 + px) << 6) + lane] = f2bf(tile[lane][px]);
    }
}

// ---------------------------------------------------------------------------
// K2 v10 (fused, software-pipelined gather): offset-conv + deform + MFMA.
//   grid: 2048 blocks of 256. Wave = px-tile.
//   THIS ROUND:
//   (1) XCD-aware block decode: b = bid & 7 so all 256 blocks of one batch
//       land on one XCD (dispatch round-robins bid%8). Per-XCD L2 working
//       set drops 8 MiB -> ~2 MiB (xT[b]+hT[b]+weights) -> gather loads
//       become L2 hits instead of L3/HBM misses.
//   (2) __launch_bounds__(256,4): raise unified-VGPR budget target from
//       3 blocks/CU (170 regs) to 4 blocks/CU (128 regs) for +33% TLP on
//       a latency-bound kernel. Core live state (~90 regs) should fit.
//   Gather loop pipelined at half-step granularity: tap k's 8 corner loads
//   (both 32-ch halves) issued before processing; tap k+1's half-0 loads
//   issued before half-1 is processed. #pragma unroll 1 pins the shape.
//   LDS arena 22272 B: rb(8448) aliases sA(4608)+sW(9216); sOff(8448) after.
// ---------------------------------------------------------------------------
__global__ __launch_bounds__(256, 4) void k2_fused(Params p) {
    __shared__ __align__(16) unsigned char arena[22272];
    unsigned short* rb = (unsigned short*)arena;            // [cg][px+2][8] bf16
    uint2*  sA   = (uint2*)arena;                           // [9][64]
    float4* sWp  = (float4*)(arena + 4608);                 // [9][64]
    float*  sOff = (float*)(arena + 13824);                 // [32][66]

    int bid = blockIdx.x;
    // XCD-aware decode: same-b blocks share an XCD's L2.
    int b = bid & 7; int gate = (bid >> 3) & 3; int row = bid >> 5;
    int t = threadIdx.x; int l = t & 63; int w = t >> 6;
    int q = l >> 4; int n = l & 15;
    int pxl = w * 16 + n;

    const unsigned short* wBp = (const unsigned short*)(p.ws + WS_WB);
    const unsigned short* owb = (const unsigned short*)(p.ws + WS_OWB);

    f32x4 acc[4];
#pragma unroll
    for (int ot = 0; ot < 4; ++ot) acc[ot] = (f32x4){0.f, 0.f, 0.f, 0.f};

    for (int sub = 0; sub < 2; ++sub) {
        int br = gate * 2 + sub;
        const unsigned short* inT =
            (const unsigned short*)(p.ws + (sub ? WS_HT : WS_XT)) + ((size_t)b << 18);
        const float* obp = p.ws + WS_OB + br * 27;

        // ---- fused offset conv: M=16 px (this wave's tile), N=32, K=576 ----
        f32x4 acc2[2];
        acc2[0] = (f32x4){0.f, 0.f, 0.f, 0.f};
        acc2[1] = (f32x4){0.f, 0.f, 0.f, 0.f};
        for (int dy = 0; dy < 3; ++dy) {
            int srow = row + dy - 1;
            __syncthreads();          // rb region free (prev phase/iter done)
#pragma unroll
            for (int ii = 0; ii < 3; ++ii) {
                int unit = t + ii * 256;
                if (unit < 528) {
                    int pxi = unit >> 3; int cg = unit & 7; int spx = pxi - 1;
                    uint4 v = {0u, 0u, 0u, 0u};
                    if (((unsigned)srow < 64u) && ((unsigned)spx < 64u))
                        v = *(const uint4*)(inT + (((size_t)srow * 64 + spx) << 6) + cg * 8);
                    *(uint4*)(rb + (cg * 66 + pxi) * 8) = v;
                }
            }
            __syncthreads();
#pragma unroll
            for (int s = 0; s < 6; ++s) {
                int dxk = s >> 1; int cgb = (s & 1) * 4 + q;
                bf16x8 af = *(const bf16x8*)(rb + (cgb * 66 + w * 16 + n + dxk) * 8);
                int kb = (br * 72 + dy * 24 + s * 4 + q) * 32;
#pragma unroll
                for (int ot = 0; ot < 2; ++ot) {
                    bf16x8 bfg = *(const bf16x8*)(owb + (size_t)(kb + ot * 16 + n) * 8);
                    acc2[ot] = __builtin_amdgcn_mfma_f32_16x16x32_bf16(af, bfg, acc2[ot], 0, 0, 0);
                }
            }
        }
        // D-frags (+bias) -> sOff[j][px]; j=ot*16+n, px=w*16+q*4+r
#pragma unroll
        for (int ot = 0; ot < 2; ++ot) {
            int j = ot * 16 + n;
            float bias = (j < 27) ? obp[j] : 0.f;
#pragma unroll
            for (int r = 0; r < 4; ++r)
                sOff[j * 66 + w * 16 + q * 4 + r] = acc2[ot][r] + bias;
        }
        __syncthreads();   // sOff visible; rb dead -> sA/sW writable

        // ---- Phase A: bilinear coords + (mask*inbound)-folded weights ----
        for (int i2 = t; i2 < 576; i2 += 256) {
            int px = i2 & 63; int k = i2 >> 6;
            float dy = sOff[(2 * k) * 66 + px];
            float dx = sOff[(2 * k + 1) * 66 + px];
            float mm = sOff[(18 + k) * 66 + px];
            float m = sigf(mm);
            int ki = k / 3, kj = k % 3;
            float py  = (float)(row + ki - 1) + dy;
            float pxx = (float)(px + kj - 1) + dx;
            float y0f = floorf(py), x0f = floorf(pxx);
            float wy = py - y0f, wx = pxx - x0f;
            int y0 = (int)y0f, x0 = (int)x0f;
            float y0i = ((unsigned)y0 < 64u) ? 1.f : 0.f;
            float y1i = ((unsigned)(y0 + 1) < 64u) ? 1.f : 0.f;
            float x0i = ((unsigned)x0 < 64u) ? 1.f : 0.f;
            float x1i = ((unsigned)(x0 + 1) < 64u) ? 1.f : 0.f;
            float w00 = (1.f - wy) * (1.f - wx) * m * y0i * x0i;
            float w01 = (1.f - wy) * wx         * m * y0i * x1i;
            float w10 = wy         * (1.f - wx) * m * y1i * x0i;
            float w11 = wy         * wx         * m * y1i * x1i;
            int cy0 = min(max(y0, 0), 63),     cy1 = min(max(y0 + 1, 0), 63);
            int cx0 = min(max(x0, 0), 63),     cx1 = min(max(x0 + 1, 0), 63);
            sA[k * 64 + px] = make_uint2((unsigned)(cy0 * 64 + cx0) | ((unsigned)(cy0 * 64 + cx1) << 16),
                                         (unsigned)(cy1 * 64 + cx0) | ((unsigned)(cy1 * 64 + cx1) << 16));
            sWp[k * 64 + px] = make_float4(w00, w01, w10, w11);
        }
        __syncthreads();

        // ---- pipelined gather into A-frags + main MFMA ----
        const unsigned short* cbase = inT + q * 8;

#define PROC(Ca, Cb, Cc, Cd, WV, S)                                            \
        {                                                                      \
            float sacc[8];                                                     \
            sacc[0] = WV.x * blo(Ca.x); sacc[1] = WV.x * bhi(Ca.x);            \
            sacc[2] = WV.x * blo(Ca.y); sacc[3] = WV.x * bhi(Ca.y);            \
            sacc[4] = WV.x * blo(Ca.z); sacc[5] = WV.x * bhi(Ca.z);            \
            sacc[6] = WV.x * blo(Ca.w); sacc[7] = WV.x * bhi(Ca.w);            \
            sacc[0] += WV.y * blo(Cb.x); sacc[1] += WV.y * bhi(Cb.x);          \
            sacc[2] += WV.y * blo(Cb.y); sacc[3] += WV.y * bhi(Cb.y);          \
            sacc[4] += WV.y * blo(Cb.z); sacc[5] += WV.y * bhi(Cb.z);          \
            sacc[6] += WV.y * blo(Cb.w); sacc[7] += WV.y * bhi(Cb.w);          \
            sacc[0] += WV.z * blo(Cc.x); sacc[1] += WV.z * bhi(Cc.x);          \
            sacc[2] += WV.z * blo(Cc.y); sacc[3] += WV.z * bhi(Cc.y);          \
            sacc[4] += WV.z * blo(Cc.z); sacc[5] += WV.z * bhi(Cc.z);          \
            sacc[6] += WV.z * blo(Cc.w); sacc[7] += WV.z * bhi(Cc.w);          \
            sacc[0] += WV.w * blo(Cd.x); sacc[1] += WV.w * bhi(Cd.x);          \
            sacc[2] += WV.w * blo(Cd.y); sacc[3] += WV.w * bhi(Cd.y);          \
            sacc[4] += WV.w * blo(Cd.z); sacc[5] += WV.w * bhi(Cd.z);          \
            sacc[6] += WV.w * blo(Cd.w); sacc[7] += WV.w * bhi(Cd.w);          \
            bf16x8 af;                                                         \
            _Pragma("unroll")                                                  \
            for (int j = 0; j < 8; ++j) af[j] = (__bf16)sacc[j];               \
            int kb = (br * 72 + (S) * 4 + q) * 64;                             \
            _Pragma("unroll")                                                  \
            for (int ot = 0; ot < 4; ++ot) {                                   \
                bf16x8 bfg = *(const bf16x8*)(wBp + (size_t)(kb + ot * 16 + n) * 8); \
                acc[ot] = __builtin_amdgcn_mfma_f32_16x16x32_bf16(af, bfg, acc[ot], 0, 0, 0); \
            }                                                                  \
        }

        // prologue: tap 0 addresses + half-0 loads
        uint2 aa = sA[pxl];
        float4 wv = sWp[pxl];
        unsigned i0 = (aa.x & 0xffffu) << 6, i1 = (aa.x >> 16) << 6;
        unsigned i2 = (aa.y & 0xffffu) << 6, i3 = (aa.y >> 16) << 6;
        uint4 C0a = *(const uint4*)(cbase + i0);
        uint4 C0b = *(const uint4*)(cbase + i1);
        uint4 C0c = *(const uint4*)(cbase + i2);
        uint4 C0d = *(const uint4*)(cbase + i3);
#pragma unroll 1
        for (int ktap = 0; ktap < 9; ++ktap) {
            // issue current tap's half-1 loads (same corners, +32 ch)
            uint4 C1a = *(const uint4*)(cbase + 32 + i0);
            uint4 C1b = *(const uint4*)(cbase + 32 + i1);
            uint4 C1c = *(const uint4*)(cbase + 32 + i2);
            uint4 C1d = *(const uint4*)(cbase + 32 + i3);
            // process half-0
            PROC(C0a, C0b, C0c, C0d, wv, ktap * 2)
            // prefetch next tap's addresses + half-0 loads
            float4 wvn = wv;
            if (ktap < 8) {
                uint2 aan = sA[(ktap + 1) * 64 + pxl];
                wvn = sWp[(ktap + 1) * 64 + pxl];
                i0 = (aan.x & 0xffffu) << 6; i1 = (aan.x >> 16) << 6;
                i2 = (aan.y & 0xffffu) << 6; i3 = (aan.y >> 16) << 6;
                C0a = *(const uint4*)(cbase + i0);
                C0b = *(const uint4*)(cbase + i1);
                C0c = *(const uint4*)(cbase + i2);
                C0d = *(const uint4*)(cbase + i3);
            }
            // process half-1
            PROC(C1a, C1b, C1c, C1d, wv, ktap * 2 + 1)
            wv = wvn;
        }
#undef PROC
        __syncthreads();   // protect sA/sW/arena before next sub's rb staging
    }

    // epilogue: direct D-scrambled coalesced store; K3 decodes.
    float* gp = p.ws + WS_GATES + ((size_t)((gate * 8 + b) * 64 + row) << 12);
#pragma unroll
    for (int ot = 0; ot < 4; ++ot)
        *(float4*)(gp + ((w * 4 + ot) * 64 + l) * 4) = *(float4*)&acc[ot];
}

// ---------------------------------------------------------------------------
// K3: pointwise ConvLSTM combine, reading D-scrambled gates (coalesced) and
//   decoding (o,px) for c/out access (16B-segment granularity).
//   grid: 8192 blocks of 256.
// ---------------------------------------------------------------------------
__global__ __launch_bounds__(256) void k3_lstm(Params p) {
    int T = blockIdx.x * 256 + threadIdx.x;        // [b][row][i] over scrambled
    int i = T & 4095; int row = (T >> 12) & 63; int b = T >> 18;
    const float* gp = p.ws + WS_GATES;
    size_t base = ((size_t)(b * 64 + row) << 12) + i;
    float gi = gp[base];
    float gf = gp[base + 1 * PLANE];
    float gc = gp[base + 2 * PLANE];
    float go = gp[base + 3 * PLANE];
    // decode scramble: i = ((w*4+ot)*64 + l)*4 + r
    int r = i & 3; int l = (i >> 2) & 63; int u = i >> 8;
    int w = u >> 2; int ot = u & 3;
    int o = ot * 16 + (l & 15);
    int px = w * 16 + (l >> 4) * 4 + r;
    size_t cidx = ((size_t)(b * 64 + o) << 12) + row * 64 + px;
    float cold = p.c[cidx];
    float ig = sigf(gi + cold * p.wci[o] + p.bi[o]);
    float fg = sigf(gf + cold * p.wcf[o] + p.bf[o]);
    float cn = fg * cold + ig * tanhfast(gc + p.bc[o]);
    float og = sigf(go + cn * p.wco[o] + p.bo[o]);
    p.out[cidx] = og * tanhfast(cn);
    p.out[cidx + PLANE] = cn;
}

// ---------------------------------------------------------------------------
extern "C" void kernel_launch(void* const* d_in, const int* in_sizes, int n_in,
                              void* d_out, int out_size, void* d_ws, size_t ws_size,
                              hipStream_t stream) {
    (void)in_sizes; (void)n_in; (void)out_size; (void)ws_size;
    Params P;
    P.x = (const float*)d_in[0];
    P.h = (const float*)d_in[1];
    P.c = (const float*)d_in[2];
    for (int i = 0; i < 8; ++i) {
        P.w[i]  = (const float*)d_in[3 + 3 * i];
        P.ow[i] = (const float*)d_in[4 + 3 * i];
        P.ob[i] = (const float*)d_in[5 + 3 * i];
    }
    P.bi  = (const float*)d_in[27];
    P.bf  = (const float*)d_in[28];
    P.bc  = (const float*)d_in[29];
    P.bo  = (const float*)d_in[30];
    P.wci = (const float*)d_in[31];
    P.wcf = (const float*)d_in[32];
    P.wco = (const float*)d_in[33];
    P.out = (float*)d_out;
    P.ws  = (float*)d_ws;

    k0_prep   <<<dim3(2753), dim3(256), 0, stream>>>(P);
    k2_fused  <<<dim3(2048), dim3(256), 0, stream>>>(P);
    k3_lstm   <<<dim3(8192), dim3(256), 0, stream>>>(P);
}

// Round 2
// 327.678 us; speedup vs baseline: 1.1298x; 1.1298x over previous
//
#include <hip/hip_runtime.h>
#include <math.h>

// Problem constants (B=8, Cin=Cout=64, H=W=64, 3x3 kernel pad 1)
#define NB     8
#define NC     64
#define HW     4096           // 64*64
#define PLANE  2097152        // NB*NC*HW

// Workspace layout (float-slot offsets)
#define WS_WB     0           // bf16 wB[8][72][64][8]   (294912 bf16 = 147456 f)
#define WS_OWB    147456      // bf16 owB[8][72][32][8]  (147456 bf16 = 73728 f)
#define WS_OB     221184      // f32 obAll[8][27]
#define WS_GATES  221400      // f32 gates_scr[4][8][64][4096] = 8388608 (D-scrambled)
#define WS_XT     8610008     // bf16 xT[8][4096][64] HWC  (1048576 f)
#define WS_HT     9658584     // bf16 hT[8][4096][64] HWC  (1048576 f)
// total = 10707160 floats = 42.8 MB

typedef __bf16 bf16x8 __attribute__((ext_vector_type(8)));
typedef float  f32x4  __attribute__((ext_vector_type(4)));

struct Params {
    const float* x; const float* h; const float* c;
    const float* w[8]; const float* ow[8]; const float* ob[8];
    const float* bi; const float* bf; const float* bc; const float* bo;
    const float* wci; const float* wcf; const float* wco;
    float* out; float* ws;
};

__device__ __forceinline__ float sigf(float v) { return 1.f / (1.f + __expf(-v)); }
__device__ __forceinline__ float tanhfast(float v) {
    return 1.f - 2.f / (__expf(2.f * v) + 1.f);
}
__device__ __forceinline__ unsigned short f2bf(float v) {
    __bf16 b = (__bf16)v;
    return __builtin_bit_cast(unsigned short, b);
}
// bf16 pair unpack: lo/hi halves of a dword -> f32 (1 inst each)
__device__ __forceinline__ float blo(unsigned d) { return __builtin_bit_cast(float, d << 16); }
__device__ __forceinline__ float bhi(unsigned d) { return __builtin_bit_cast(float, d & 0xffff0000u); }

// ---------------------------------------------------------------------------
// K0 (merged): weight B-frag packing + biases (blocks 0..1728), and
//   CHW fp32 -> HWC bf16 transpose of x/h (blocks 1729..2752).
// ---------------------------------------------------------------------------
__global__ __launch_bounds__(256) void k0_prep(Params p) {
    if (blockIdx.x < 1729) {
        int i = blockIdx.x * 256 + threadIdx.x;
        unsigned short* wb  = (unsigned short*)(p.ws + WS_WB);
        unsigned short* owb = (unsigned short*)(p.ws + WS_OWB);
        if (i < 294912) {
            int br = i / 36864; int r = i % 36864;
            int kgrp = r >> 9; int o = (r >> 3) & 63; int j = r & 7;
            int k = kgrp * 8 + j;
            int ktap = k >> 6; int c = k & 63;
            wb[i] = f2bf(p.w[br][(o * 64 + c) * 9 + ktap]);
        } else if (i < 294912 + 147456) {
            int ii = i - 294912;
            int br = ii / 18432; int r = ii % 18432;
            int kgrp = r >> 8; int o = (r >> 3) & 31; int j = r & 7;
            int k = kgrp * 8 + j;
            int ktap = k >> 6; int c = k & 63;
            float v = (o < 27) ? p.ow[br][(o * 64 + c) * 9 + ktap] : 0.f;
            owb[ii] = f2bf(v);
        } else if (i < 294912 + 147456 + 216) {
            int ii = i - 442368;
            int br = ii / 27; int j = ii % 27;
            p.ws[WS_OB + ii] = p.ob[br][j];
        }
        return;
    }
    __shared__ float tile[64][65];
    int bid = blockIdx.x - 1729;
    int row = bid & 63; int b = (bid >> 6) & 7; int ten = bid >> 9;
    const float* src = ten ? p.h : p.x;
    unsigned short* dst = (unsigned short*)(p.ws + (ten ? WS_HT : WS_XT));
    int t = threadIdx.x; int lane = t & 63; int w4 = t >> 6;
#pragma unroll
    for (int i = 0; i < 16; ++i) {
        int c = i * 4 + w4;
        tile[c][lane] = src[((size_t)(b * 64 + c) << 12) + row * 64 + lane];
    }
    __syncthreads();
#pragma unroll
    for (int i = 0; i < 16; ++i) {
        int px = i * 4 + w4;
        dst[((size_t)(b * 4096 + row * 64 + px) << 6) + lane] = f2bf(tile[lane][px]);
    }
}

// ---------------------------------------------------------------------------
// K2 v11 (fused, software-pipelined gather): offset-conv + deform + MFMA.
//   grid: 2048 blocks of 256. Wave = px-tile.
//   R1 post-mortem: __launch_bounds__(256,4) forced VGPR 84->64 and spilled
//   (WRITE_SIZE 33->132 MB, dur +8%). The deep gather pipeline needs the
//   full 3-block register budget — REVERTED to (256,3).
//   KEPT: XCD-aware block decode (b = bid & 7): all 256 blocks of one batch
//   land on one XCD (dispatch round-robins bid%8). Per-XCD L2 working set
//   drops ~9 MiB -> ~1.9 MiB (xT[b]+hT[b]+weights) -> gathers become L2
//   hits instead of L3 misses. This round isolates that change.
//   Gather loop pipelined at half-step granularity: tap k's 8 corner loads
//   (both 32-ch halves) issued before processing; tap k+1's half-0 loads
//   issued before half-1 is processed. #pragma unroll 1 pins the shape.
//   LDS arena 22272 B: rb(8448) aliases sA(4608)+sW(9216); sOff(8448) after.
// ---------------------------------------------------------------------------
__global__ __launch_bounds__(256, 3) void k2_fused(Params p) {
    __shared__ __align__(16) unsigned char arena[22272];
    unsigned short* rb = (unsigned short*)arena;            // [cg][px+2][8] bf16
    uint2*  sA   = (uint2*)arena;                           // [9][64]
    float4* sWp  = (float4*)(arena + 4608);                 // [9][64]
    float*  sOff = (float*)(arena + 13824);                 // [32][66]

    int bid = blockIdx.x;
    // XCD-aware decode: same-b blocks share an XCD's L2.
    int b = bid & 7; int gate = (bid >> 3) & 3; int row = bid >> 5;
    int t = threadIdx.x; int l = t & 63; int w = t >> 6;
    int q = l >> 4; int n = l & 15;
    int pxl = w * 16 + n;

    const unsigned short* wBp = (const unsigned short*)(p.ws + WS_WB);
    const unsigned short* owb = (const unsigned short*)(p.ws + WS_OWB);

    f32x4 acc[4];
#pragma unroll
    for (int ot = 0; ot < 4; ++ot) acc[ot] = (f32x4){0.f, 0.f, 0.f, 0.f};

    for (int sub = 0; sub < 2; ++sub) {
        int br = gate * 2 + sub;
        const unsigned short* inT =
            (const unsigned short*)(p.ws + (sub ? WS_HT : WS_XT)) + ((size_t)b << 18);
        const float* obp = p.ws + WS_OB + br * 27;

        // ---- fused offset conv: M=16 px (this wave's tile), N=32, K=576 ----
        f32x4 acc2[2];
        acc2[0] = (f32x4){0.f, 0.f, 0.f, 0.f};
        acc2[1] = (f32x4){0.f, 0.f, 0.f, 0.f};
        for (int dy = 0; dy < 3; ++dy) {
            int srow = row + dy - 1;
            __syncthreads();          // rb region free (prev phase/iter done)
#pragma unroll
            for (int ii = 0; ii < 3; ++ii) {
                int unit = t + ii * 256;
                if (unit < 528) {
                    int pxi = unit >> 3; int cg = unit & 7; int spx = pxi - 1;
                    uint4 v = {0u, 0u, 0u, 0u};
                    if (((unsigned)srow < 64u) && ((unsigned)spx < 64u))
                        v = *(const uint4*)(inT + (((size_t)srow * 64 + spx) << 6) + cg * 8);
                    *(uint4*)(rb + (cg * 66 + pxi) * 8) = v;
                }
            }
            __syncthreads();
#pragma unroll
            for (int s = 0; s < 6; ++s) {
                int dxk = s >> 1; int cgb = (s & 1) * 4 + q;
                bf16x8 af = *(const bf16x8*)(rb + (cgb * 66 + w * 16 + n + dxk) * 8);
                int kb = (br * 72 + dy * 24 + s * 4 + q) * 32;
#pragma unroll
                for (int ot = 0; ot < 2; ++ot) {
                    bf16x8 bfg = *(const bf16x8*)(owb + (size_t)(kb + ot * 16 + n) * 8);
                    acc2[ot] = __builtin_amdgcn_mfma_f32_16x16x32_bf16(af, bfg, acc2[ot], 0, 0, 0);
                }
            }
        }
        // D-frags (+bias) -> sOff[j][px]; j=ot*16+n, px=w*16+q*4+r
#pragma unroll
        for (int ot = 0; ot < 2; ++ot) {
            int j = ot * 16 + n;
            float bias = (j < 27) ? obp[j] : 0.f;
#pragma unroll
            for (int r = 0; r < 4; ++r)
                sOff[j * 66 + w * 16 + q * 4 + r] = acc2[ot][r] + bias;
        }
        __syncthreads();   // sOff visible; rb dead -> sA/sW writable

        // ---- Phase A: bilinear coords + (mask*inbound)-folded weights ----
        for (int i2 = t; i2 < 576; i2 += 256) {
            int px = i2 & 63; int k = i2 >> 6;
            float dy = sOff[(2 * k) * 66 + px];
            float dx = sOff[(2 * k + 1) * 66 + px];
            float mm = sOff[(18 + k) * 66 + px];
            float m = sigf(mm);
            int ki = k / 3, kj = k % 3;
            float py  = (float)(row + ki - 1) + dy;
            float pxx = (float)(px + kj - 1) + dx;
            float y0f = floorf(py), x0f = floorf(pxx);
            float wy = py - y0f, wx = pxx - x0f;
            int y0 = (int)y0f, x0 = (int)x0f;
            float y0i = ((unsigned)y0 < 64u) ? 1.f : 0.f;
            float y1i = ((unsigned)(y0 + 1) < 64u) ? 1.f : 0.f;
            float x0i = ((unsigned)x0 < 64u) ? 1.f : 0.f;
            float x1i = ((unsigned)(x0 + 1) < 64u) ? 1.f : 0.f;
            float w00 = (1.f - wy) * (1.f - wx) * m * y0i * x0i;
            float w01 = (1.f - wy) * wx         * m * y0i * x1i;
            float w10 = wy         * (1.f - wx) * m * y1i * x0i;
            float w11 = wy         * wx         * m * y1i * x1i;
            int cy0 = min(max(y0, 0), 63),     cy1 = min(max(y0 + 1, 0), 63);
            int cx0 = min(max(x0, 0), 63),     cx1 = min(max(x0 + 1, 0), 63);
            sA[k * 64 + px] = make_uint2((unsigned)(cy0 * 64 + cx0) | ((unsigned)(cy0 * 64 + cx1) << 16),
                                         (unsigned)(cy1 * 64 + cx0) | ((unsigned)(cy1 * 64 + cx1) << 16));
            sWp[k * 64 + px] = make_float4(w00, w01, w10, w11);
        }
        __syncthreads();

        // ---- pipelined gather into A-frags + main MFMA ----
        const unsigned short* cbase = inT + q * 8;

#define PROC(Ca, Cb, Cc, Cd, WV, S)                                            \
        {                                                                      \
            float sacc[8];                                                     \
            sacc[0] = WV.x * blo(Ca.x); sacc[1] = WV.x * bhi(Ca.x);            \
            sacc[2] = WV.x * blo(Ca.y); sacc[3] = WV.x * bhi(Ca.y);            \
            sacc[4] = WV.x * blo(Ca.z); sacc[5] = WV.x * bhi(Ca.z);            \
            sacc[6] = WV.x * blo(Ca.w); sacc[7] = WV.x * bhi(Ca.w);            \
            sacc[0] += WV.y * blo(Cb.x); sacc[1] += WV.y * bhi(Cb.x);          \
            sacc[2] += WV.y * blo(Cb.y); sacc[3] += WV.y * bhi(Cb.y);          \
            sacc[4] += WV.y * blo(Cb.z); sacc[5] += WV.y * bhi(Cb.z);          \
            sacc[6] += WV.y * blo(Cb.w); sacc[7] += WV.y * bhi(Cb.w);          \
            sacc[0] += WV.z * blo(Cc.x); sacc[1] += WV.z * bhi(Cc.x);          \
            sacc[2] += WV.z * blo(Cc.y); sacc[3] += WV.z * bhi(Cc.y);          \
            sacc[4] += WV.z * blo(Cc.z); sacc[5] += WV.z * bhi(Cc.z);          \
            sacc[6] += WV.z * blo(Cc.w); sacc[7] += WV.z * bhi(Cc.w);          \
            sacc[0] += WV.w * blo(Cd.x); sacc[1] += WV.w * bhi(Cd.x);          \
            sacc[2] += WV.w * blo(Cd.y); sacc[3] += WV.w * bhi(Cd.y);          \
            sacc[4] += WV.w * blo(Cd.z); sacc[5] += WV.w * bhi(Cd.z);          \
            sacc[6] += WV.w * blo(Cd.w); sacc[7] += WV.w * bhi(Cd.w);          \
            bf16x8 af;                                                         \
            _Pragma("unroll")                                                  \
            for (int j = 0; j < 8; ++j) af[j] = (__bf16)sacc[j];               \
            int kb = (br * 72 + (S) * 4 + q) * 64;                             \
            _Pragma("unroll")                                                  \
            for (int ot = 0; ot < 4; ++ot) {                                   \
                bf16x8 bfg = *(const bf16x8*)(wBp + (size_t)(kb + ot * 16 + n) * 8); \
                acc[ot] = __builtin_amdgcn_mfma_f32_16x16x32_bf16(af, bfg, acc[ot], 0, 0, 0); \
            }                                                                  \
        }

        // prologue: tap 0 addresses + half-0 loads
        uint2 aa = sA[pxl];
        float4 wv = sWp[pxl];
        unsigned i0 = (aa.x & 0xffffu) << 6, i1 = (aa.x >> 16) << 6;
        unsigned i2 = (aa.y & 0xffffu) << 6, i3 = (aa.y >> 16) << 6;
        uint4 C0a = *(const uint4*)(cbase + i0);
        uint4 C0b = *(const uint4*)(cbase + i1);
        uint4 C0c = *(const uint4*)(cbase + i2);
        uint4 C0d = *(const uint4*)(cbase + i3);
#pragma unroll 1
        for (int ktap = 0; ktap < 9; ++ktap) {
            // issue current tap's half-1 loads (same corners, +32 ch)
            uint4 C1a = *(const uint4*)(cbase + 32 + i0);
            uint4 C1b = *(const uint4*)(cbase + 32 + i1);
            uint4 C1c = *(const uint4*)(cbase + 32 + i2);
            uint4 C1d = *(const uint4*)(cbase + 32 + i3);
            // process half-0
            PROC(C0a, C0b, C0c, C0d, wv, ktap * 2)
            // prefetch next tap's addresses + half-0 loads
            float4 wvn = wv;
            if (ktap < 8) {
                uint2 aan = sA[(ktap + 1) * 64 + pxl];
                wvn = sWp[(ktap + 1) * 64 + pxl];
                i0 = (aan.x & 0xffffu) << 6; i1 = (aan.x >> 16) << 6;
                i2 = (aan.y & 0xffffu) << 6; i3 = (aan.y >> 16) << 6;
                C0a = *(const uint4*)(cbase + i0);
                C0b = *(const uint4*)(cbase + i1);
                C0c = *(const uint4*)(cbase + i2);
                C0d = *(const uint4*)(cbase + i3);
            }
            // process half-1
            PROC(C1a, C1b, C1c, C1d, wv, ktap * 2 + 1)
            wv = wvn;
        }
#undef PROC
        __syncthreads();   // protect sA/sW/arena before next sub's rb staging
    }

    // epilogue: direct D-scrambled coalesced store; K3 decodes.
    float* gp = p.ws + WS_GATES + ((size_t)((gate * 8 + b) * 64 + row) << 12);
#pragma unroll
    for (int ot = 0; ot < 4; ++ot)
        *(float4*)(gp + ((w * 4 + ot) * 64 + l) * 4) = *(float4*)&acc[ot];
}

// ---------------------------------------------------------------------------
// K3: pointwise ConvLSTM combine, reading D-scrambled gates (coalesced) and
//   decoding (o,px) for c/out access (16B-segment granularity).
//   grid: 8192 blocks of 256.
// ---------------------------------------------------------------------------
__global__ __launch_bounds__(256) void k3_lstm(Params p) {
    int T = blockIdx.x * 256 + threadIdx.x;        // [b][row][i] over scrambled
    int i = T & 4095; int row = (T >> 12) & 63; int b = T >> 18;
    const float* gp = p.ws + WS_GATES;
    size_t base = ((size_t)(b * 64 + row) << 12) + i;
    float gi = gp[base];
    float gf = gp[base + 1 * PLANE];
    float gc = gp[base + 2 * PLANE];
    float go = gp[base + 3 * PLANE];
    // decode scramble: i = ((w*4+ot)*64 + l)*4 + r
    int r = i & 3; int l = (i >> 2) & 63; int u = i >> 8;
    int w = u >> 2; int ot = u & 3;
    int o = ot * 16 + (l & 15);
    int px = w * 16 + (l >> 4) * 4 + r;
    size_t cidx = ((size_t)(b * 64 + o) << 12) + row * 64 + px;
    float cold = p.c[cidx];
    float ig = sigf(gi + cold * p.wci[o] + p.bi[o]);
    float fg = sigf(gf + cold * p.wcf[o] + p.bf[o]);
    float cn = fg * cold + ig * tanhfast(gc + p.bc[o]);
    float og = sigf(go + cn * p.wco[o] + p.bo[o]);
    p.out[cidx] = og * tanhfast(cn);
    p.out[cidx + PLANE] = cn;
}

// ---------------------------------------------------------------------------
extern "C" void kernel_launch(void* const* d_in, const int* in_sizes, int n_in,
                              void* d_out, int out_size, void* d_ws, size_t ws_size,
                              hipStream_t stream) {
    (void)in_sizes; (void)n_in; (void)out_size; (void)ws_size;
    Params P;
    P.x = (const float*)d_in[0];
    P.h = (const float*)d_in[1];
    P.c = (const float*)d_in[2];
    for (int i = 0; i < 8; ++i) {
        P.w[i]  = (const float*)d_in[3 + 3 * i];
        P.ow[i] = (const float*)d_in[4 + 3 * i];
        P.ob[i] = (const float*)d_in[5 + 3 * i];
    }
    P.bi  = (const float*)d_in[27];
    P.bf  = (const float*)d_in[28];
    P.bc  = (const float*)d_in[29];
    P.bo  = (const float*)d_in[30];
    P.wci = (const float*)d_in[31];
    P.wcf = (const float*)d_in[32];
    P.wco = (const float*)d_in[33];
    P.out = (float*)d_out;
    P.ws  = (float*)d_ws;

    k0_prep   <<<dim3(2753), dim3(256), 0, stream>>>(P);
    k2_fused  <<<dim3(2048), dim3(256), 0, stream>>>(P);
    k3_lstm   <<<dim3(8192), dim3(256), 0, stream>>>(P);
}

// Round 4
// 276.677 us; speedup vs baseline: 1.3381x; 1.1843x over previous
//
#include <hip/hip_runtime.h>
#include <math.h>

// Problem constants (B=8, Cin=Cout=64, H=W=64, 3x3 kernel pad 1)
#define NB     8
#define NC     64
#define HW     4096           // 64*64
#define PLANE  2097152        // NB*NC*HW

// Workspace layout (float-slot offsets)
#define WS_WB     0           // bf16 wB[8][72][64][8]   (294912 bf16 = 147456 f)
#define WS_OWB    147456      // bf16 owB[8][72][32][8]  (147456 bf16 = 73728 f)
#define WS_OB     221184      // f32 obAll[8][27]
#define WS_GATES  221400      // f32 gates_scr[4][8][64][4096] = 8388608 (D-scrambled)
#define WS_XT     8610008     // bf16 xT[8][4096][64] HWC  (1048576 f)
#define WS_HT     9658584     // bf16 hT[8][4096][64] HWC  (1048576 f)
// total = 10707160 floats = 42.8 MB

typedef __bf16 bf16x8 __attribute__((ext_vector_type(8)));
typedef float  f32x4  __attribute__((ext_vector_type(4)));

struct Params {
    const float* x; const float* h; const float* c;
    const float* w[8]; const float* ow[8]; const float* ob[8];
    const float* bi; const float* bf; const float* bc; const float* bo;
    const float* wci; const float* wcf; const float* wco;
    float* out; float* ws;
};

__device__ __forceinline__ float sigf(float v) { return 1.f / (1.f + __expf(-v)); }
__device__ __forceinline__ float tanhfast(float v) {
    return 1.f - 2.f / (__expf(2.f * v) + 1.f);
}
__device__ __forceinline__ unsigned short f2bf(float v) {
    __bf16 b = (__bf16)v;
    return __builtin_bit_cast(unsigned short, b);
}
// bf16 pair unpack: lo/hi halves of a dword -> f32 (1 inst each)
__device__ __forceinline__ float blo(unsigned d) { return __builtin_bit_cast(float, d << 16); }
__device__ __forceinline__ float bhi(unsigned d) { return __builtin_bit_cast(float, d & 0xffff0000u); }

// ---------------------------------------------------------------------------
// K0 (merged): weight B-frag packing + biases (blocks 0..1728), and
//   CHW fp32 -> HWC bf16 transpose of x/h (blocks 1729..2752).
// ---------------------------------------------------------------------------
__global__ __launch_bounds__(256) void k0_prep(Params p) {
    if (blockIdx.x < 1729) {
        int i = blockIdx.x * 256 + threadIdx.x;
        unsigned short* wb  = (unsigned short*)(p.ws + WS_WB);
        unsigned short* owb = (unsigned short*)(p.ws + WS_OWB);
        if (i < 294912) {
            int br = i / 36864; int r = i % 36864;
            int kgrp = r >> 9; int o = (r >> 3) & 63; int j = r & 7;
            int k = kgrp * 8 + j;
            int ktap = k >> 6; int c = k & 63;
            wb[i] = f2bf(p.w[br][(o * 64 + c) * 9 + ktap]);
        } else if (i < 294912 + 147456) {
            int ii = i - 294912;
            int br = ii / 18432; int r = ii % 18432;
            int kgrp = r >> 8; int o = (r >> 3) & 31; int j = r & 7;
            int k = kgrp * 8 + j;
            int ktap = k >> 6; int c = k & 63;
            float v = (o < 27) ? p.ow[br][(o * 64 + c) * 9 + ktap] : 0.f;
            owb[ii] = f2bf(v);
        } else if (i < 294912 + 147456 + 216) {
            int ii = i - 442368;
            int br = ii / 27; int j = ii % 27;
            p.ws[WS_OB + ii] = p.ob[br][j];
        }
        return;
    }
    __shared__ float tile[64][65];
    int bid = blockIdx.x - 1729;
    int row = bid & 63; int b = (bid >> 6) & 7; int ten = bid >> 9;
    const float* src = ten ? p.h : p.x;
    unsigned short* dst = (unsigned short*)(p.ws + (ten ? WS_HT : WS_XT));
    int t = threadIdx.x; int lane = t & 63; int w4 = t >> 6;
#pragma unroll
    for (int i = 0; i < 16; ++i) {
        int c = i * 4 + w4;
        tile[c][lane] = src[((size_t)(b * 64 + c) << 12) + row * 64 + lane];
    }
    __syncthreads();
#pragma unroll
    for (int i = 0; i < 16; ++i) {
        int px = i * 4 + w4;
        dst[((size_t)(b * 4096 + row * 64 + px) << 6) + lane] = f2bf(tile[lane][px]);
    }
}

// ---------------------------------------------------------------------------
// K2 v12 (LDS-gather): offset-conv + deform + MFMA, gather served from LDS.
//   (Resubmission of R3 — container failed before measuring; source audited
//   for fault vectors: LDS/global bounds, swizzle bijectivity, no hangs.)
//   R2 post-mortem: gathers were L2-resident (FETCH 35->7.6MB) yet waves
//   still ~90% stalled -> the vector-memory path itself (L1 thrash / 16
//   scattered 64B lines per load inst / MSHR+TA queue) is the bottleneck,
//   not HBM/L3 locality. Fix: stage the 5-row window (rows row-2..row+2,
//   40KB, zero-filled OOB) in LDS once per sub; the bilinear gather and the
//   offset-conv both read it. Global gather traffic per block-sub drops
//   288KB scattered -> 41KB coalesced (~7x), barriers 9->4 per sub.
//   Correctness: offsets are data-dependent; phase A sets a 'far' bit when
//   a (clamped) corner row falls outside the staged window; those lanes
//   take a per-lane global-load fallback identical to the old path.
//   (Zero-weight corners read staged-but-arbitrary finite data: w==0.)
//   LDS XOR swizzle on BOTH writer and reader: byte ^= (px&7)<<4 spreads
//   the 128B-strided pixel bases across 8 bank-groups (2-way = free).
//   LDS 63232B -> 2 blocks/CU (__launch_bounds__(256,2); reg budget 256,
//   no spill risk for the 16-uint4-deep pipeline).
//   Decode keeps R2's proven XCD swizzle: b = bid&7.
// ---------------------------------------------------------------------------
__global__ __launch_bounds__(256, 2) void k2_fused(Params p) {
    __shared__ __align__(16) unsigned char arena[63232];
    // rows:  [0, 40960)      bf16 [5][64px][64ch], byte=((r*64+px)<<7)+seg*16 ^ ((px&7)<<4)
    // sA:    [40960, 45568)  uint2 [9][64]  packed clamped pix (+far bit31 in .x)
    // sWp:   [45568, 54784)  float4 [9][64] folded bilinear weights
    // sOff:  [54784, 63232)  f32 [32][66]
    uint2*  sA   = (uint2*)(arena + 40960);
    float4* sWp  = (float4*)(arena + 45568);
    float*  sOff = (float*)(arena + 54784);

    int bid = blockIdx.x;
    // XCD-aware decode: same-b blocks share an XCD's L2.
    int b = bid & 7; int gate = (bid >> 3) & 3; int row = bid >> 5;
    int t = threadIdx.x; int l = t & 63; int w = t >> 6;
    int q = l >> 4; int n = l & 15;
    int pxl = w * 16 + n;

    const unsigned short* wBp = (const unsigned short*)(p.ws + WS_WB);
    const unsigned short* owb = (const unsigned short*)(p.ws + WS_OWB);

    // per-lane gather address bias: byte = (pix<<7) + qb, then ^ ((pix&7)<<4)
    int qb = q * 16 - (row - 2) * 8192;

    f32x4 acc[4];
#pragma unroll
    for (int ot = 0; ot < 4; ++ot) acc[ot] = (f32x4){0.f, 0.f, 0.f, 0.f};

    for (int sub = 0; sub < 2; ++sub) {
        int br = gate * 2 + sub;
        const unsigned short* inT =
            (const unsigned short*)(p.ws + (sub ? WS_HT : WS_XT)) + ((size_t)b << 18);
        const float* obp = p.ws + WS_OB + br * 27;

        // ---- stage 5-row window (rows row-2..row+2, zero-filled OOB) ----
        __syncthreads();           // rows/sA/sWp free (prev sub's gather done)
#pragma unroll
        for (int it = 0; it < 10; ++it) {
            int u = t + it * 256;                  // u in [0,2560)
            int r = u >> 9; int px = (u >> 3) & 63; int seg = u & 7;
            int grow = row - 2 + r;
            uint4 v = {0u, 0u, 0u, 0u};
            if ((unsigned)grow < 64u)
                v = *(const uint4*)(inT + (((size_t)grow * 64 + px) << 6) + seg * 8);
            unsigned byte = ((unsigned)u << 4) ^ (((unsigned)px & 7u) << 4);
            *(uint4*)(arena + byte) = v;
        }
        __syncthreads();

        // ---- fused offset conv: M=16 px (this wave's tile), N=32, K=576 ----
        f32x4 acc2[2];
        acc2[0] = (f32x4){0.f, 0.f, 0.f, 0.f};
        acc2[1] = (f32x4){0.f, 0.f, 0.f, 0.f};
#pragma unroll
        for (int dy = 0; dy < 3; ++dy) {
#pragma unroll
            for (int s = 0; s < 6; ++s) {
                int dxk = s >> 1; int cgb = (s & 1) * 4 + q;
                int spx = w * 16 + n + dxk - 1;               // [-1, 64]
                int spc = min(max(spx, 0), 63);
                unsigned byte = ((unsigned)(((dy + 1) * 64 + spc) << 7) + cgb * 16)
                                ^ (((unsigned)spc & 7u) << 4);
                bf16x8 af = *(const bf16x8*)(arena + byte);
                if ((unsigned)spx >= 64u) {                   // zero halo columns
#pragma unroll
                    for (int z = 0; z < 8; ++z) af[z] = (__bf16)0.f;
                }
                int kb = (br * 72 + dy * 24 + s * 4 + q) * 32;
#pragma unroll
                for (int ot = 0; ot < 2; ++ot) {
                    bf16x8 bfg = *(const bf16x8*)(owb + (size_t)(kb + ot * 16 + n) * 8);
                    acc2[ot] = __builtin_amdgcn_mfma_f32_16x16x32_bf16(af, bfg, acc2[ot], 0, 0, 0);
                }
            }
        }
        // D-frags (+bias) -> sOff[j][px]; j=ot*16+n, px=w*16+q*4+r
#pragma unroll
        for (int ot = 0; ot < 2; ++ot) {
            int j = ot * 16 + n;
            float bias = (j < 27) ? obp[j] : 0.f;
#pragma unroll
            for (int r = 0; r < 4; ++r)
                sOff[j * 66 + w * 16 + q * 4 + r] = acc2[ot][r] + bias;
        }
        __syncthreads();   // sOff visible

        // ---- Phase A: bilinear coords + (mask*inbound)-folded weights ----
        for (int i2 = t; i2 < 576; i2 += 256) {
            int px = i2 & 63; int k = i2 >> 6;
            float dy = sOff[(2 * k) * 66 + px];
            float dx = sOff[(2 * k + 1) * 66 + px];
            float mm = sOff[(18 + k) * 66 + px];
            float m = sigf(mm);
            int ki = k / 3, kj = k % 3;
            float py  = (float)(row + ki - 1) + dy;
            float pxx = (float)(px + kj - 1) + dx;
            float y0f = floorf(py), x0f = floorf(pxx);
            float wy = py - y0f, wx = pxx - x0f;
            int y0 = (int)y0f, x0 = (int)x0f;
            float y0i = ((unsigned)y0 < 64u) ? 1.f : 0.f;
            float y1i = ((unsigned)(y0 + 1) < 64u) ? 1.f : 0.f;
            float x0i = ((unsigned)x0 < 64u) ? 1.f : 0.f;
            float x1i = ((unsigned)(x0 + 1) < 64u) ? 1.f : 0.f;
            float w00 = (1.f - wy) * (1.f - wx) * m * y0i * x0i;
            float w01 = (1.f - wy) * wx         * m * y0i * x1i;
            float w10 = wy         * (1.f - wx) * m * y1i * x0i;
            float w11 = wy         * wx         * m * y1i * x1i;
            int cy0 = min(max(y0, 0), 63),     cy1 = min(max(y0 + 1, 0), 63);
            int cx0 = min(max(x0, 0), 63),     cx1 = min(max(x0 + 1, 0), 63);
            // far: clamped corner row outside staged window [row-2, row+2]
            int s0 = cy0 - (row - 2); int s1 = cy1 - (row - 2);
            unsigned farb = (((unsigned)s0 > 4u) || ((unsigned)s1 > 4u)) ? 0x80000000u : 0u;
            sA[k * 64 + px] = make_uint2(((unsigned)(cy0 * 64 + cx0) | ((unsigned)(cy0 * 64 + cx1) << 16)) | farb,
                                         (unsigned)(cy1 * 64 + cx0) | ((unsigned)(cy1 * 64 + cx1) << 16));
            sWp[k * 64 + px] = make_float4(w00, w01, w10, w11);
        }
        __syncthreads();

        // ---- pipelined LDS gather into A-frags + main MFMA ----
        const unsigned short* cbase = inT + q * 8;

#define PROC(Ca, Cb, Cc, Cd, WV, S)                                            \
        {                                                                      \
            float sacc[8];                                                     \
            sacc[0] = WV.x * blo(Ca.x); sacc[1] = WV.x * bhi(Ca.x);            \
            sacc[2] = WV.x * blo(Ca.y); sacc[3] = WV.x * bhi(Ca.y);            \
            sacc[4] = WV.x * blo(Ca.z); sacc[5] = WV.x * bhi(Ca.z);            \
            sacc[6] = WV.x * blo(Ca.w); sacc[7] = WV.x * bhi(Ca.w);            \
            sacc[0] += WV.y * blo(Cb.x); sacc[1] += WV.y * bhi(Cb.x);          \
            sacc[2] += WV.y * blo(Cb.y); sacc[3] += WV.y * bhi(Cb.y);          \
            sacc[4] += WV.y * blo(Cb.z); sacc[5] += WV.y * bhi(Cb.z);          \
            sacc[6] += WV.y * blo(Cb.w); sacc[7] += WV.y * bhi(Cb.w);          \
            sacc[0] += WV.z * blo(Cc.x); sacc[1] += WV.z * bhi(Cc.x);          \
            sacc[2] += WV.z * blo(Cc.y); sacc[3] += WV.z * bhi(Cc.y);          \
            sacc[4] += WV.z * blo(Cc.z); sacc[5] += WV.z * bhi(Cc.z);          \
            sacc[6] += WV.z * blo(Cc.w); sacc[7] += WV.z * bhi(Cc.w);          \
            sacc[0] += WV.w * blo(Cd.x); sacc[1] += WV.w * bhi(Cd.x);          \
            sacc[2] += WV.w * blo(Cd.y); sacc[3] += WV.w * bhi(Cd.y);          \
            sacc[4] += WV.w * blo(Cd.z); sacc[5] += WV.w * bhi(Cd.z);          \
            sacc[6] += WV.w * blo(Cd.w); sacc[7] += WV.w * bhi(Cd.w);          \
            bf16x8 af;                                                         \
            _Pragma("unroll")                                                  \
            for (int j = 0; j < 8; ++j) af[j] = (__bf16)sacc[j];               \
            int kb = (br * 72 + (S) * 4 + q) * 64;                             \
            _Pragma("unroll")                                                  \
            for (int ot = 0; ot < 4; ++ot) {                                   \
                bf16x8 bfg = *(const bf16x8*)(wBp + (size_t)(kb + ot * 16 + n) * 8); \
                acc[ot] = __builtin_amdgcn_mfma_f32_16x16x32_bf16(af, bfg, acc[ot], 0, 0, 0); \
            }                                                                  \
        }

        // prologue: tap 0 addresses + all 8 corner-half LDS loads
        uint2 aa = sA[pxl];
        float4 wv = sWp[pxl];
        unsigned p00 = aa.x & 0xFFFu, p01 = (aa.x >> 16) & 0xFFFu;
        unsigned p10 = aa.y & 0xFFFu, p11 = aa.y >> 16;
        unsigned a00 = (unsigned)(((int)(p00 << 7)) + qb) ^ ((p00 & 7u) << 4);
        unsigned a01 = (unsigned)(((int)(p01 << 7)) + qb) ^ ((p01 & 7u) << 4);
        unsigned a10 = (unsigned)(((int)(p10 << 7)) + qb) ^ ((p10 & 7u) << 4);
        unsigned a11 = (unsigned)(((int)(p11 << 7)) + qb) ^ ((p11 & 7u) << 4);
        uint4 C0a = *(const uint4*)(arena + a00);
        uint4 C0b = *(const uint4*)(arena + a01);
        uint4 C0c = *(const uint4*)(arena + a10);
        uint4 C0d = *(const uint4*)(arena + a11);
        uint4 C1a = *(const uint4*)(arena + (a00 ^ 64u));
        uint4 C1b = *(const uint4*)(arena + (a01 ^ 64u));
        uint4 C1c = *(const uint4*)(arena + (a10 ^ 64u));
        uint4 C1d = *(const uint4*)(arena + (a11 ^ 64u));
        if (aa.x & 0x80000000u) {     // rare: window miss -> exact global path
            C0a = *(const uint4*)(cbase + (p00 << 6));
            C0b = *(const uint4*)(cbase + (p01 << 6));
            C0c = *(const uint4*)(cbase + (p10 << 6));
            C0d = *(const uint4*)(cbase + (p11 << 6));
            C1a = *(const uint4*)(cbase + (p00 << 6) + 32);
            C1b = *(const uint4*)(cbase + (p01 << 6) + 32);
            C1c = *(const uint4*)(cbase + (p10 << 6) + 32);
            C1d = *(const uint4*)(cbase + (p11 << 6) + 32);
        }
#pragma unroll 1
        for (int ktap = 0; ktap < 9; ++ktap) {
            uint4 N0a = C0a, N0b = C0b, N0c = C0c, N0d = C0d;
            uint4 N1a = C1a, N1b = C1b, N1c = C1c, N1d = C1d;
            float4 wvn = wv;
            if (ktap < 8) {      // prefetch next tap (both halves) from LDS
                uint2 aan = sA[(ktap + 1) * 64 + pxl];
                wvn = sWp[(ktap + 1) * 64 + pxl];
                unsigned q00 = aan.x & 0xFFFu, q01 = (aan.x >> 16) & 0xFFFu;
                unsigned q10 = aan.y & 0xFFFu, q11 = aan.y >> 16;
                unsigned b00 = (unsigned)(((int)(q00 << 7)) + qb) ^ ((q00 & 7u) << 4);
                unsigned b01 = (unsigned)(((int)(q01 << 7)) + qb) ^ ((q01 & 7u) << 4);
                unsigned b10 = (unsigned)(((int)(q10 << 7)) + qb) ^ ((q10 & 7u) << 4);
                unsigned b11 = (unsigned)(((int)(q11 << 7)) + qb) ^ ((q11 & 7u) << 4);
                N0a = *(const uint4*)(arena + b00);
                N0b = *(const uint4*)(arena + b01);
                N0c = *(const uint4*)(arena + b10);
                N0d = *(const uint4*)(arena + b11);
                N1a = *(const uint4*)(arena + (b00 ^ 64u));
                N1b = *(const uint4*)(arena + (b01 ^ 64u));
                N1c = *(const uint4*)(arena + (b10 ^ 64u));
                N1d = *(const uint4*)(arena + (b11 ^ 64u));
                if (aan.x & 0x80000000u) {
                    N0a = *(const uint4*)(cbase + (q00 << 6));
                    N0b = *(const uint4*)(cbase + (q01 << 6));
                    N0c = *(const uint4*)(cbase + (q10 << 6));
                    N0d = *(const uint4*)(cbase + (q11 << 6));
                    N1a = *(const uint4*)(cbase + (q00 << 6) + 32);
                    N1b = *(const uint4*)(cbase + (q01 << 6) + 32);
                    N1c = *(const uint4*)(cbase + (q10 << 6) + 32);
                    N1d = *(const uint4*)(cbase + (q11 << 6) + 32);
                }
            }
            // process current tap (half-0 then half-1)
            PROC(C0a, C0b, C0c, C0d, wv, ktap * 2)
            PROC(C1a, C1b, C1c, C1d, wv, ktap * 2 + 1)
            C0a = N0a; C0b = N0b; C0c = N0c; C0d = N0d;
            C1a = N1a; C1b = N1b; C1c = N1c; C1d = N1d;
            wv = wvn;
        }
#undef PROC
    }

    // epilogue: direct D-scrambled coalesced store; K3 decodes.
    float* gp = p.ws + WS_GATES + ((size_t)((gate * 8 + b) * 64 + row) << 12);
#pragma unroll
    for (int ot = 0; ot < 4; ++ot)
        *(float4*)(gp + ((w * 4 + ot) * 64 + l) * 4) = *(float4*)&acc[ot];
}

// ---------------------------------------------------------------------------
// K3: pointwise ConvLSTM combine, reading D-scrambled gates (coalesced) and
//   decoding (o,px) for c/out access (16B-segment granularity).
//   grid: 8192 blocks of 256.
// ---------------------------------------------------------------------------
__global__ __launch_bounds__(256) void k3_lstm(Params p) {
    int T = blockIdx.x * 256 + threadIdx.x;        // [b][row][i] over scrambled
    int i = T & 4095; int row = (T >> 12) & 63; int b = T >> 18;
    const float* gp = p.ws + WS_GATES;
    size_t base = ((size_t)(b * 64 + row) << 12) + i;
    float gi = gp[base];
    float gf = gp[base + 1 * PLANE];
    float gc = gp[base + 2 * PLANE];
    float go = gp[base + 3 * PLANE];
    // decode scramble: i = ((w*4+ot)*64 + l)*4 + r
    int r = i & 3; int l = (i >> 2) & 63; int u = i >> 8;
    int w = u >> 2; int ot = u & 3;
    int o = ot * 16 + (l & 15);
    int px = w * 16 + (l >> 4) * 4 + r;
    size_t cidx = ((size_t)(b * 64 + o) << 12) + row * 64 + px;
    float cold = p.c[cidx];
    float ig = sigf(gi + cold * p.wci[o] + p.bi[o]);
    float fg = sigf(gf + cold * p.wcf[o] + p.bf[o]);
    float cn = fg * cold + ig * tanhfast(gc + p.bc[o]);
    float og = sigf(go + cn * p.wco[o] + p.bo[o]);
    p.out[cidx] = og * tanhfast(cn);
    p.out[cidx + PLANE] = cn;
}

// ---------------------------------------------------------------------------
extern "C" void kernel_launch(void* const* d_in, const int* in_sizes, int n_in,
                              void* d_out, int out_size, void* d_ws, size_t ws_size,
                              hipStream_t stream) {
    (void)in_sizes; (void)n_in; (void)out_size; (void)ws_size;
    Params P;
    P.x = (const float*)d_in[0];
    P.h = (const float*)d_in[1];
    P.c = (const float*)d_in[2];
    for (int i = 0; i < 8; ++i) {
        P.w[i]  = (const float*)d_in[3 + 3 * i];
        P.ow[i] = (const float*)d_in[4 + 3 * i];
        P.ob[i] = (const float*)d_in[5 + 3 * i];
    }
    P.bi  = (const float*)d_in[27];
    P.bf  = (const float*)d_in[28];
    P.bc  = (const float*)d_in[29];
    P.bo  = (const float*)d_in[30];
    P.wci = (const float*)d_in[31];
    P.wcf = (const float*)d_in[32];
    P.wco = (const float*)d_in[33];
    P.out = (float*)d_out;
    P.ws  = (float*)d_ws;

    k0_prep   <<<dim3(2753), dim3(256), 0, stream>>>(P);
    k2_fused  <<<dim3(2048), dim3(256), 0, stream>>>(P);
    k3_lstm   <<<dim3(8192), dim3(256), 0, stream>>>(P);
}

// Round 5
// 274.602 us; speedup vs baseline: 1.3482x; 1.0076x over previous
//
#include <hip/hip_runtime.h>
#include <math.h>

// Problem constants (B=8, Cin=Cout=64, H=W=64, 3x3 kernel pad 1)
#define NB     8
#define NC     64
#define HW     4096           // 64*64
#define PLANE  2097152        // NB*NC*HW

// Workspace layout (float-slot offsets)
#define WS_WB     0           // bf16 wB[8][72][64][8]   (294912 bf16 = 147456 f)
#define WS_OWB    147456      // bf16 owB[8][72][32][8]  (147456 bf16 = 73728 f)
#define WS_OB     221184      // f32 obAll[8][27]
#define WS_GATES  221400      // f32 gates_scr[4][8][64][4096] = 8388608 (D-scrambled)
#define WS_XT     8610008     // bf16 xT[8][4096][64] HWC  (1048576 f)
#define WS_HT     9658584     // bf16 hT[8][4096][64] HWC  (1048576 f)
// total = 10707160 floats = 42.8 MB

typedef __bf16 bf16x8 __attribute__((ext_vector_type(8)));
typedef float  f32x4  __attribute__((ext_vector_type(4)));

struct Params {
    const float* x; const float* h; const float* c;
    const float* w[8]; const float* ow[8]; const float* ob[8];
    const float* bi; const float* bf; const float* bc; const float* bo;
    const float* wci; const float* wcf; const float* wco;
    float* out; float* ws;
};

__device__ __forceinline__ float sigf(float v) { return 1.f / (1.f + __expf(-v)); }
__device__ __forceinline__ float tanhfast(float v) {
    return 1.f - 2.f / (__expf(2.f * v) + 1.f);
}
__device__ __forceinline__ unsigned short f2bf(float v) {
    __bf16 b = (__bf16)v;
    return __builtin_bit_cast(unsigned short, b);
}
// bf16 pair unpack: lo/hi halves of a dword -> f32 (1 inst each)
__device__ __forceinline__ float blo(unsigned d) { return __builtin_bit_cast(float, d << 16); }
__device__ __forceinline__ float bhi(unsigned d) { return __builtin_bit_cast(float, d & 0xffff0000u); }

// ---------------------------------------------------------------------------
// K0 (merged): weight B-frag packing + biases (blocks 0..1728), and
//   CHW fp32 -> HWC bf16 transpose of x/h (blocks 1729..2752).
// ---------------------------------------------------------------------------
__global__ __launch_bounds__(256) void k0_prep(Params p) {
    if (blockIdx.x < 1729) {
        int i = blockIdx.x * 256 + threadIdx.x;
        unsigned short* wb  = (unsigned short*)(p.ws + WS_WB);
        unsigned short* owb = (unsigned short*)(p.ws + WS_OWB);
        if (i < 294912) {
            int br = i / 36864; int r = i % 36864;
            int kgrp = r >> 9; int o = (r >> 3) & 63; int j = r & 7;
            int k = kgrp * 8 + j;
            int ktap = k >> 6; int c = k & 63;
            wb[i] = f2bf(p.w[br][(o * 64 + c) * 9 + ktap]);
        } else if (i < 294912 + 147456) {
            int ii = i - 294912;
            int br = ii / 18432; int r = ii % 18432;
            int kgrp = r >> 8; int o = (r >> 3) & 31; int j = r & 7;
            int k = kgrp * 8 + j;
            int ktap = k >> 6; int c = k & 63;
            float v = (o < 27) ? p.ow[br][(o * 64 + c) * 9 + ktap] : 0.f;
            owb[ii] = f2bf(v);
        } else if (i < 294912 + 147456 + 216) {
            int ii = i - 442368;
            int br = ii / 27; int j = ii % 27;
            p.ws[WS_OB + ii] = p.ob[br][j];
        }
        return;
    }
    __shared__ float tile[64][65];
    int bid = blockIdx.x - 1729;
    int row = bid & 63; int b = (bid >> 6) & 7; int ten = bid >> 9;
    const float* src = ten ? p.h : p.x;
    unsigned short* dst = (unsigned short*)(p.ws + (ten ? WS_HT : WS_XT));
    int t = threadIdx.x; int lane = t & 63; int w4 = t >> 6;
#pragma unroll
    for (int i = 0; i < 16; ++i) {
        int c = i * 4 + w4;
        tile[c][lane] = src[((size_t)(b * 64 + c) << 12) + row * 64 + lane];
    }
    __syncthreads();
#pragma unroll
    for (int i = 0; i < 16; ++i) {
        int px = i * 4 + w4;
        dst[((size_t)(b * 4096 + row * 64 + px) << 6) + lane] = f2bf(tile[lane][px]);
    }
}

// ---------------------------------------------------------------------------
// K2 v13 (B-frag software pipeline): offset-conv + deform + MFMA.
//   R4 post-mortem: per-block wall ~87k cycles vs ~12k fully-pipelined
//   estimate; the A-side (gather) was pipelined but BOTH MFMA loops loaded
//   B-fragments from GLOBAL (wBp/owb, L2-resident, ~250cy) immediately
//   before the dependent MFMA -> per-step vmcnt stalls dominate. Occupancy
//   is LDS-capped at 2 blocks/CU, so VGPR headroom (budget 256/wave) is
//   free: THIS ROUND pipelines B-frags one step ahead in registers in both
//   loops (+~70 VGPR), and splits the offset-conv accumulator into 4
//   chains (manual 2-step unroll; no runtime-indexed vector arrays).
//   Carried: 5-row LDS window gather (R4, -49us), XOR bank swizzle, far-bit
//   global fallback, XCD swizzle b=bid&7, D-scrambled epilogue.
//   LDS 63232B -> 2 blocks/CU. Grid 2048x256.
// ---------------------------------------------------------------------------
__global__ __launch_bounds__(256, 2) void k2_fused(Params p) {
    __shared__ __align__(16) unsigned char arena[63232];
    // rows:  [0, 40960)      bf16 [5][64px][64ch], byte=((r*64+px)<<7)+seg*16 ^ ((px&7)<<4)
    // sA:    [40960, 45568)  uint2 [9][64]  packed clamped pix (+far bit31 in .x)
    // sWp:   [45568, 54784)  float4 [9][64] folded bilinear weights
    // sOff:  [54784, 63232)  f32 [32][66]
    uint2*  sA   = (uint2*)(arena + 40960);
    float4* sWp  = (float4*)(arena + 45568);
    float*  sOff = (float*)(arena + 54784);

    int bid = blockIdx.x;
    // XCD-aware decode: same-b blocks share an XCD's L2.
    int b = bid & 7; int gate = (bid >> 3) & 3; int row = bid >> 5;
    int t = threadIdx.x; int l = t & 63; int w = t >> 6;
    int q = l >> 4; int n = l & 15;
    int pxl = w * 16 + n;

    const unsigned short* wBp = (const unsigned short*)(p.ws + WS_WB);
    const unsigned short* owb = (const unsigned short*)(p.ws + WS_OWB);

    // per-lane gather address bias: byte = (pix<<7) + qb, then ^ ((pix&7)<<4)
    int qb = q * 16 - (row - 2) * 8192;

    f32x4 acc[4];
#pragma unroll
    for (int ot = 0; ot < 4; ++ot) acc[ot] = (f32x4){0.f, 0.f, 0.f, 0.f};

    for (int sub = 0; sub < 2; ++sub) {
        int br = gate * 2 + sub;
        const unsigned short* inT =
            (const unsigned short*)(p.ws + (sub ? WS_HT : WS_XT)) + ((size_t)b << 18);
        const float* obp = p.ws + WS_OB + br * 27;

        // ---- stage 5-row window (rows row-2..row+2, zero-filled OOB) ----
        __syncthreads();           // rows/sA/sWp free (prev sub's gather done)
#pragma unroll
        for (int it = 0; it < 10; ++it) {
            int u = t + it * 256;                  // u in [0,2560)
            int r = u >> 9; int px = (u >> 3) & 63; int seg = u & 7;
            int grow = row - 2 + r;
            uint4 v = {0u, 0u, 0u, 0u};
            if ((unsigned)grow < 64u)
                v = *(const uint4*)(inT + (((size_t)grow * 64 + px) << 6) + seg * 8);
            unsigned byte = ((unsigned)u << 4) ^ (((unsigned)px & 7u) << 4);
            *(uint4*)(arena + byte) = v;
        }
        __syncthreads();

        // ---- fused offset conv (pipelined): M=16 px, N=32, K=576 ----
        // K-slice u = dy*6+s; A from LDS window, B from global (prefetched
        // one 2-step group ahead); 4 accumulator chains.
        auto loadA_oc = [&](int u) -> bf16x8 {
            int dy = u / 6; int s = u - dy * 6;
            int spx = w * 16 + n + (s >> 1) - 1;              // [-1, 64]
            int spc = min(max(spx, 0), 63);
            int cgb = (s & 1) * 4 + q;
            unsigned byte = ((unsigned)(((dy + 1) * 64 + spc) << 7) + cgb * 16)
                            ^ (((unsigned)spc & 7u) << 4);
            bf16x8 af = *(const bf16x8*)(arena + byte);
            if ((unsigned)spx >= 64u) {                       // zero halo columns
#pragma unroll
                for (int z = 0; z < 8; ++z) af[z] = (__bf16)0.f;
            }
            return af;
        };
        auto loadB_oc = [&](int u, int ot) -> bf16x8 {
            int dy = u / 6; int s = u - dy * 6;
            int kb = (br * 72 + dy * 24 + s * 4 + q) * 32;
            return *(const bf16x8*)(owb + (size_t)(kb + ot * 16 + n) * 8);
        };
        f32x4 a2c0 = (f32x4){0.f,0.f,0.f,0.f}, a2c1 = (f32x4){0.f,0.f,0.f,0.f};
        f32x4 a2c2 = (f32x4){0.f,0.f,0.f,0.f}, a2c3 = (f32x4){0.f,0.f,0.f,0.f};
        bf16x8 eA = loadA_oc(0), eB0 = loadB_oc(0, 0), eB1 = loadB_oc(0, 1);
        bf16x8 dA = loadA_oc(1), dB0 = loadB_oc(1, 0), dB1 = loadB_oc(1, 1);
#pragma unroll 1
        for (int u2 = 0; u2 < 9; ++u2) {
            bf16x8 neA = eA, neB0 = eB0, neB1 = eB1;
            bf16x8 ndA = dA, ndB0 = dB0, ndB1 = dB1;
            if (u2 < 8) {
                neA = loadA_oc(2 * u2 + 2); neB0 = loadB_oc(2 * u2 + 2, 0); neB1 = loadB_oc(2 * u2 + 2, 1);
                ndA = loadA_oc(2 * u2 + 3); ndB0 = loadB_oc(2 * u2 + 3, 0); ndB1 = loadB_oc(2 * u2 + 3, 1);
            }
            a2c0 = __builtin_amdgcn_mfma_f32_16x16x32_bf16(eA, eB0, a2c0, 0, 0, 0);
            a2c1 = __builtin_amdgcn_mfma_f32_16x16x32_bf16(eA, eB1, a2c1, 0, 0, 0);
            a2c2 = __builtin_amdgcn_mfma_f32_16x16x32_bf16(dA, dB0, a2c2, 0, 0, 0);
            a2c3 = __builtin_amdgcn_mfma_f32_16x16x32_bf16(dA, dB1, a2c3, 0, 0, 0);
            eA = neA; eB0 = neB0; eB1 = neB1;
            dA = ndA; dB0 = ndB0; dB1 = ndB1;
        }
        f32x4 acc2[2];
        acc2[0] = a2c0 + a2c2;
        acc2[1] = a2c1 + a2c3;

        // D-frags (+bias) -> sOff[j][px]; j=ot*16+n, px=w*16+q*4+r
#pragma unroll
        for (int ot = 0; ot < 2; ++ot) {
            int j = ot * 16 + n;
            float bias = (j < 27) ? obp[j] : 0.f;
#pragma unroll
            for (int r = 0; r < 4; ++r)
                sOff[j * 66 + w * 16 + q * 4 + r] = acc2[ot][r] + bias;
        }
        __syncthreads();   // sOff visible

        // ---- Phase A: bilinear coords + (mask*inbound)-folded weights ----
        for (int i2 = t; i2 < 576; i2 += 256) {
            int px = i2 & 63; int k = i2 >> 6;
            float dy = sOff[(2 * k) * 66 + px];
            float dx = sOff[(2 * k + 1) * 66 + px];
            float mm = sOff[(18 + k) * 66 + px];
            float m = sigf(mm);
            int ki = k / 3, kj = k % 3;
            float py  = (float)(row + ki - 1) + dy;
            float pxx = (float)(px + kj - 1) + dx;
            float y0f = floorf(py), x0f = floorf(pxx);
            float wy = py - y0f, wx = pxx - x0f;
            int y0 = (int)y0f, x0 = (int)x0f;
            float y0i = ((unsigned)y0 < 64u) ? 1.f : 0.f;
            float y1i = ((unsigned)(y0 + 1) < 64u) ? 1.f : 0.f;
            float x0i = ((unsigned)x0 < 64u) ? 1.f : 0.f;
            float x1i = ((unsigned)(x0 + 1) < 64u) ? 1.f : 0.f;
            float w00 = (1.f - wy) * (1.f - wx) * m * y0i * x0i;
            float w01 = (1.f - wy) * wx         * m * y0i * x1i;
            float w10 = wy         * (1.f - wx) * m * y1i * x0i;
            float w11 = wy         * wx         * m * y1i * x1i;
            int cy0 = min(max(y0, 0), 63),     cy1 = min(max(y0 + 1, 0), 63);
            int cx0 = min(max(x0, 0), 63),     cx1 = min(max(x0 + 1, 0), 63);
            // far: clamped corner row outside staged window [row-2, row+2]
            int s0 = cy0 - (row - 2); int s1 = cy1 - (row - 2);
            unsigned farb = (((unsigned)s0 > 4u) || ((unsigned)s1 > 4u)) ? 0x80000000u : 0u;
            sA[k * 64 + px] = make_uint2(((unsigned)(cy0 * 64 + cx0) | ((unsigned)(cy0 * 64 + cx1) << 16)) | farb,
                                         (unsigned)(cy1 * 64 + cx0) | ((unsigned)(cy1 * 64 + cx1) << 16));
            sWp[k * 64 + px] = make_float4(w00, w01, w10, w11);
        }
        __syncthreads();

        // ---- pipelined LDS gather + B-frag register double-buffer + MFMA ----
        const unsigned short* cbase = inT + q * 8;
        auto loadB_mn = [&](int S, int ot) -> bf16x8 {
            int kb = (br * 72 + S * 4 + q) * 64;
            return *(const bf16x8*)(wBp + (size_t)(kb + ot * 16 + n) * 8);
        };

#define PROC(Ca, Cb, Cc, Cd, WV, Wa, Wb, Wc, Wd)                               \
        {                                                                      \
            float sacc[8];                                                     \
            sacc[0] = WV.x * blo(Ca.x); sacc[1] = WV.x * bhi(Ca.x);            \
            sacc[2] = WV.x * blo(Ca.y); sacc[3] = WV.x * bhi(Ca.y);            \
            sacc[4] = WV.x * blo(Ca.z); sacc[5] = WV.x * bhi(Ca.z);            \
            sacc[6] = WV.x * blo(Ca.w); sacc[7] = WV.x * bhi(Ca.w);            \
            sacc[0] += WV.y * blo(Cb.x); sacc[1] += WV.y * bhi(Cb.x);          \
            sacc[2] += WV.y * blo(Cb.y); sacc[3] += WV.y * bhi(Cb.y);          \
            sacc[4] += WV.y * blo(Cb.z); sacc[5] += WV.y * bhi(Cb.z);          \
            sacc[6] += WV.y * blo(Cb.w); sacc[7] += WV.y * bhi(Cb.w);          \
            sacc[0] += WV.z * blo(Cc.x); sacc[1] += WV.z * bhi(Cc.x);          \
            sacc[2] += WV.z * blo(Cc.y); sacc[3] += WV.z * bhi(Cc.y);          \
            sacc[4] += WV.z * blo(Cc.z); sacc[5] += WV.z * bhi(Cc.z);          \
            sacc[6] += WV.z * blo(Cc.w); sacc[7] += WV.z * bhi(Cc.w);          \
            sacc[0] += WV.w * blo(Cd.x); sacc[1] += WV.w * bhi(Cd.x);          \
            sacc[2] += WV.w * blo(Cd.y); sacc[3] += WV.w * bhi(Cd.y);          \
            sacc[4] += WV.w * blo(Cd.z); sacc[5] += WV.w * bhi(Cd.z);          \
            sacc[6] += WV.w * blo(Cd.w); sacc[7] += WV.w * bhi(Cd.w);          \
            bf16x8 af;                                                         \
            _Pragma("unroll")                                                  \
            for (int j = 0; j < 8; ++j) af[j] = (__bf16)sacc[j];               \
            acc[0] = __builtin_amdgcn_mfma_f32_16x16x32_bf16(af, Wa, acc[0], 0, 0, 0); \
            acc[1] = __builtin_amdgcn_mfma_f32_16x16x32_bf16(af, Wb, acc[1], 0, 0, 0); \
            acc[2] = __builtin_amdgcn_mfma_f32_16x16x32_bf16(af, Wc, acc[2], 0, 0, 0); \
            acc[3] = __builtin_amdgcn_mfma_f32_16x16x32_bf16(af, Wd, acc[3], 0, 0, 0); \
        }

        // prologue: tap 0 addresses, corner LDS loads, and tap-0 B-frags
        uint2 aa = sA[pxl];
        float4 wv = sWp[pxl];
        unsigned p00 = aa.x & 0xFFFu, p01 = (aa.x >> 16) & 0xFFFu;
        unsigned p10 = aa.y & 0xFFFu, p11 = aa.y >> 16;
        unsigned a00 = (unsigned)(((int)(p00 << 7)) + qb) ^ ((p00 & 7u) << 4);
        unsigned a01 = (unsigned)(((int)(p01 << 7)) + qb) ^ ((p01 & 7u) << 4);
        unsigned a10 = (unsigned)(((int)(p10 << 7)) + qb) ^ ((p10 & 7u) << 4);
        unsigned a11 = (unsigned)(((int)(p11 << 7)) + qb) ^ ((p11 & 7u) << 4);
        uint4 C0a = *(const uint4*)(arena + a00);
        uint4 C0b = *(const uint4*)(arena + a01);
        uint4 C0c = *(const uint4*)(arena + a10);
        uint4 C0d = *(const uint4*)(arena + a11);
        uint4 C1a = *(const uint4*)(arena + (a00 ^ 64u));
        uint4 C1b = *(const uint4*)(arena + (a01 ^ 64u));
        uint4 C1c = *(const uint4*)(arena + (a10 ^ 64u));
        uint4 C1d = *(const uint4*)(arena + (a11 ^ 64u));
        if (aa.x & 0x80000000u) {     // rare: window miss -> exact global path
            C0a = *(const uint4*)(cbase + (p00 << 6));
            C0b = *(const uint4*)(cbase + (p01 << 6));
            C0c = *(const uint4*)(cbase + (p10 << 6));
            C0d = *(const uint4*)(cbase + (p11 << 6));
            C1a = *(const uint4*)(cbase + (p00 << 6) + 32);
            C1b = *(const uint4*)(cbase + (p01 << 6) + 32);
            C1c = *(const uint4*)(cbase + (p10 << 6) + 32);
            C1d = *(const uint4*)(cbase + (p11 << 6) + 32);
        }
        bf16x8 B0a = loadB_mn(0, 0), B0b = loadB_mn(0, 1), B0c = loadB_mn(0, 2), B0d = loadB_mn(0, 3);
        bf16x8 B1a = loadB_mn(1, 0), B1b = loadB_mn(1, 1), B1c = loadB_mn(1, 2), B1d = loadB_mn(1, 3);
#pragma unroll 1
        for (int ktap = 0; ktap < 9; ++ktap) {
            uint4 N0a = C0a, N0b = C0b, N0c = C0c, N0d = C0d;
            uint4 N1a = C1a, N1b = C1b, N1c = C1c, N1d = C1d;
            float4 wvn = wv;
            bf16x8 nB0a = B0a, nB0b = B0b, nB0c = B0c, nB0d = B0d;
            bf16x8 nB1a = B1a, nB1b = B1b, nB1c = B1c, nB1d = B1d;
            if (ktap < 8) {      // prefetch next tap: A corners (LDS) + B frags (global)
                uint2 aan = sA[(ktap + 1) * 64 + pxl];
                wvn = sWp[(ktap + 1) * 64 + pxl];
                unsigned q00 = aan.x & 0xFFFu, q01 = (aan.x >> 16) & 0xFFFu;
                unsigned q10 = aan.y & 0xFFFu, q11 = aan.y >> 16;
                unsigned b00 = (unsigned)(((int)(q00 << 7)) + qb) ^ ((q00 & 7u) << 4);
                unsigned b01 = (unsigned)(((int)(q01 << 7)) + qb) ^ ((q01 & 7u) << 4);
                unsigned b10 = (unsigned)(((int)(q10 << 7)) + qb) ^ ((q10 & 7u) << 4);
                unsigned b11 = (unsigned)(((int)(q11 << 7)) + qb) ^ ((q11 & 7u) << 4);
                N0a = *(const uint4*)(arena + b00);
                N0b = *(const uint4*)(arena + b01);
                N0c = *(const uint4*)(arena + b10);
                N0d = *(const uint4*)(arena + b11);
                N1a = *(const uint4*)(arena + (b00 ^ 64u));
                N1b = *(const uint4*)(arena + (b01 ^ 64u));
                N1c = *(const uint4*)(arena + (b10 ^ 64u));
                N1d = *(const uint4*)(arena + (b11 ^ 64u));
                if (aan.x & 0x80000000u) {
                    N0a = *(const uint4*)(cbase + (q00 << 6));
                    N0b = *(const uint4*)(cbase + (q01 << 6));
                    N0c = *(const uint4*)(cbase + (q10 << 6));
                    N0d = *(const uint4*)(cbase + (q11 << 6));
                    N1a = *(const uint4*)(cbase + (q00 << 6) + 32);
                    N1b = *(const uint4*)(cbase + (q01 << 6) + 32);
                    N1c = *(const uint4*)(cbase + (q10 << 6) + 32);
                    N1d = *(const uint4*)(cbase + (q11 << 6) + 32);
                }
                nB0a = loadB_mn(2 * ktap + 2, 0); nB0b = loadB_mn(2 * ktap + 2, 1);
                nB0c = loadB_mn(2 * ktap + 2, 2); nB0d = loadB_mn(2 * ktap + 2, 3);
                nB1a = loadB_mn(2 * ktap + 3, 0); nB1b = loadB_mn(2 * ktap + 3, 1);
                nB1c = loadB_mn(2 * ktap + 3, 2); nB1d = loadB_mn(2 * ktap + 3, 3);
            }
            // process current tap (half-0 then half-1) with preloaded B
            PROC(C0a, C0b, C0c, C0d, wv, B0a, B0b, B0c, B0d)
            PROC(C1a, C1b, C1c, C1d, wv, B1a, B1b, B1c, B1d)
            C0a = N0a; C0b = N0b; C0c = N0c; C0d = N0d;
            C1a = N1a; C1b = N1b; C1c = N1c; C1d = N1d;
            B0a = nB0a; B0b = nB0b; B0c = nB0c; B0d = nB0d;
            B1a = nB1a; B1b = nB1b; B1c = nB1c; B1d = nB1d;
            wv = wvn;
        }
#undef PROC
    }

    // epilogue: direct D-scrambled coalesced store; K3 decodes.
    float* gp = p.ws + WS_GATES + ((size_t)((gate * 8 + b) * 64 + row) << 12);
#pragma unroll
    for (int ot = 0; ot < 4; ++ot)
        *(float4*)(gp + ((w * 4 + ot) * 64 + l) * 4) = *(float4*)&acc[ot];
}

// ---------------------------------------------------------------------------
// K3: pointwise ConvLSTM combine, reading D-scrambled gates (coalesced) and
//   decoding (o,px) for c/out access (16B-segment granularity).
//   grid: 8192 blocks of 256.
// ---------------------------------------------------------------------------
__global__ __launch_bounds__(256) void k3_lstm(Params p) {
    int T = blockIdx.x * 256 + threadIdx.x;        // [b][row][i] over scrambled
    int i = T & 4095; int row = (T >> 12) & 63; int b = T >> 18;
    const float* gp = p.ws + WS_GATES;
    size_t base = ((size_t)(b * 64 + row) << 12) + i;
    float gi = gp[base];
    float gf = gp[base + 1 * PLANE];
    float gc = gp[base + 2 * PLANE];
    float go = gp[base + 3 * PLANE];
    // decode scramble: i = ((w*4+ot)*64 + l)*4 + r
    int r = i & 3; int l = (i >> 2) & 63; int u = i >> 8;
    int w = u >> 2; int ot = u & 3;
    int o = ot * 16 + (l & 15);
    int px = w * 16 + (l >> 4) * 4 + r;
    size_t cidx = ((size_t)(b * 64 + o) << 12) + row * 64 + px;
    float cold = p.c[cidx];
    float ig = sigf(gi + cold * p.wci[o] + p.bi[o]);
    float fg = sigf(gf + cold * p.wcf[o] + p.bf[o]);
    float cn = fg * cold + ig * tanhfast(gc + p.bc[o]);
    float og = sigf(go + cn * p.wco[o] + p.bo[o]);
    p.out[cidx] = og * tanhfast(cn);
    p.out[cidx + PLANE] = cn;
}

// ---------------------------------------------------------------------------
extern "C" void kernel_launch(void* const* d_in, const int* in_sizes, int n_in,
                              void* d_out, int out_size, void* d_ws, size_t ws_size,
                              hipStream_t stream) {
    (void)in_sizes; (void)n_in; (void)out_size; (void)ws_size;
    Params P;
    P.x = (const float*)d_in[0];
    P.h = (const float*)d_in[1];
    P.c = (const float*)d_in[2];
    for (int i = 0; i < 8; ++i) {
        P.w[i]  = (const float*)d_in[3 + 3 * i];
        P.ow[i] = (const float*)d_in[4 + 3 * i];
        P.ob[i] = (const float*)d_in[5 + 3 * i];
    }
    P.bi  = (const float*)d_in[27];
    P.bf  = (const float*)d_in[28];
    P.bc  = (const float*)d_in[29];
    P.bo  = (const float*)d_in[30];
    P.wci = (const float*)d_in[31];
    P.wcf = (const float*)d_in[32];
    P.wco = (const float*)d_in[33];
    P.out = (float*)d_out;
    P.ws  = (float*)d_ws;

    k0_prep   <<<dim3(2753), dim3(256), 0, stream>>>(P);
    k2_fused  <<<dim3(2048), dim3(256), 0, stream>>>(P);
    k3_lstm   <<<dim3(8192), dim3(256), 0, stream>>>(P);
}